// Round 12
// baseline (145.105 us; speedup 1.0000x reference)
//
#include <hip/hip_runtime.h>
#include <hip/hip_bf16.h>
#include <math.h>

#define NN 1024
#define CC 128
#define C2 64
#define KK 16
#define NCAND 24

#if __has_builtin(__builtin_amdgcn_exp2f)
#define EXP2F(x) __builtin_amdgcn_exp2f(x)
#else
#define EXP2F(x) exp2f(x)
#endif
#define LOG2E 1.4426950408889634f

typedef short short8 __attribute__((ext_vector_type(8)));
typedef float f32x4  __attribute__((ext_vector_type(4)));
typedef int   int4v  __attribute__((ext_vector_type(4)));
typedef unsigned int uint;

__device__ __forceinline__ float fast_rcp(float x) {
    return __builtin_amdgcn_rcpf(x);
}
__device__ __forceinline__ unsigned short f2bf(float x) {   // RNE f32->bf16
    unsigned int u = __float_as_uint(x);
    unsigned int r = (u + 0x7FFFu + ((u >> 16) & 1u)) >> 16;
    return (unsigned short)r;
}
__device__ __forceinline__ float bf2f(unsigned short h) {
    return __uint_as_float(((unsigned int)h) << 16);
}

// In-wave LDS write->read visibility: wait LDS ops, pin compiler order.
#define LDS_FENCE() do { \
    asm volatile("s_waitcnt lgkmcnt(0)" ::: "memory"); \
    __builtin_amdgcn_sched_barrier(0); } while (0)

// ---------------- K0: A = M^T M, f32, ascending-r fmaf chain (np-exact) ----
__global__ __launch_bounds__(256) void buildA(const float* __restrict__ M,
                                              float* __restrict__ A) {
    const int e = blockIdx.x * 256 + threadIdx.x;    // 4096 entries
    const int c = e >> 6, d = e & 63;
    float acc = 0.f;
    #pragma unroll 8
    for (int r = 0; r < C2; ++r)
        acc = fmaf(M[r * C2 + c], M[r * C2 + d], acc);
    A[e] = acc;                                      // A[c][d] row-major
}

// ---------------- K1: projections + logmap, f32 (np-exact) + psE -----------
__global__ __launch_bounds__(128) void proj(
        const float* __restrict__ X,
        const float* __restrict__ Wm,
        const float* __restrict__ Ws,
        float* __restrict__ pm,
        float* __restrict__ ps,
        float* __restrict__ psE) {
    const int bn = blockIdx.x;           // b*1024 + n
    const int b  = bn >> 10;
    const int n  = bn & (NN - 1);
    const int t  = threadIdx.x;          // 0..127

    __shared__ float xv[CC];
    xv[t] = X[b * CC * NN + t * NN + n];
    __syncthreads();

    const int d = t & (C2 - 1);
    const float* wr = ((t < C2) ? Wm : Ws) + d * CC;
    float acc = 0.f;
    #pragma unroll
    for (int c = 0; c < CC; ++c)
        acc = fmaf(wr[c], xv[c], acc);   // sequential k-order, single acc

    float a = __fadd_rn(fabsf(acc), 1e-10f);
    float l = logf(a);
    float r = (acc > 0.f) ? l : ((acc < 0.f) ? -l : 0.f);
    if (t < C2) {
        pm[bn * C2 + d] = r;
    } else {
        ps[bn * C2 + d] = r;
        psE[bn * C2 + d] = EXP2F(r * LOG2E);   // e^ps (proxy pass only)
    }
}

// ---------------- K2: 2 waves per row, 2048 blocks x 128 thr ---------------
//  A: proxy dis2 via bf16 3-term-split MFMA; wave w does j-tiles w*32..+31
//  B: per-wave (redundant) top-24 candidates via packed-uint min passes
//  C: wave w rescores candidates w*12..+11 with R6's EXACT np-f32 op order
//  F: wave 0 top-16 on exact diff (desc, index asc) -> out
// launch_bounds (128,3): VGPR cap 170 >= natural ~140 -> NO SPILL.
// R11's (128,4) forced 64-VGPR target -> 41 MB spill writes, win erased.
__global__ __launch_bounds__(128, 3) void pair_topk(
        const float* __restrict__ pm,
        const float* __restrict__ ps,
        const float* __restrict__ psE,
        const float* __restrict__ Mf,
        const float* __restrict__ A,
        float* __restrict__ out) {
    const int tid  = threadIdx.x;
    const int wv   = tid >> 6;           // 0..1
    const int lane = tid & 63;
    const int g    = lane >> 4;          // k-group 0..3
    const int lj   = lane & 15;          // col (B) / row (A) within tile

    const int bi = blockIdx.x;           // row 0..2047
    const int b  = bi >> 10;
    const int i  = bi & (NN - 1);

    __shared__ uint  d2u[NN];            // packed (d2 & ~0x3FF) | j
    __shared__ float sC[2][C2];
    __shared__ float cdiffL[NCAND];

    const float* psb  = ps  + b * NN * C2;
    const float* psEb = psE + b * NN * C2;

    const float pm_own = pm[bi * C2 + lane];         // exact (phase C)

    float pmEf[2][8];
    #pragma unroll
    for (int kt = 0; kt < 2; ++kt) {
        const float4 a0 = *(const float4*)(pm + bi * C2 + kt * 32 + g * 8);
        const float4 a1 = *(const float4*)(pm + bi * C2 + kt * 32 + g * 8 + 4);
        pmEf[kt][0] = EXP2F(a0.x * LOG2E); pmEf[kt][1] = EXP2F(a0.y * LOG2E);
        pmEf[kt][2] = EXP2F(a0.z * LOG2E); pmEf[kt][3] = EXP2F(a0.w * LOG2E);
        pmEf[kt][4] = EXP2F(a1.x * LOG2E); pmEf[kt][5] = EXP2F(a1.y * LOG2E);
        pmEf[kt][6] = EXP2F(a1.z * LOG2E); pmEf[kt][7] = EXP2F(a1.w * LOG2E);
    }

    // ---- Phase A (scoped so M fragments die before phase C) ----
    {
        short8 ahi[4][2], alo[4][2];     // M rows hi/lo bf16 (RNE, once)
        #pragma unroll
        for (int rt = 0; rt < 4; ++rt) {
            #pragma unroll
            for (int kt = 0; kt < 2; ++kt) {
                const float* mrow = Mf + (rt * 16 + lj) * C2 + kt * 32 + g * 8;
                const float4 m0 = *(const float4*)mrow;
                const float4 m1 = *(const float4*)(mrow + 4);
                float mv[8] = {m0.x, m0.y, m0.z, m0.w, m1.x, m1.y, m1.z, m1.w};
                #pragma unroll
                for (int e = 0; e < 8; ++e) {
                    unsigned short h = f2bf(mv[e]);
                    ahi[rt][kt][e] = (short)h;
                    alo[rt][kt][e] = (short)f2bf(mv[e] - bf2f(h));
                }
            }
        }

        #pragma unroll 2
        for (int t5 = 0; t5 < 32; ++t5) {
            const int jt = wv * 32 + t5;
            const int j  = jt * 16 + lj;
            const float* pjE = psEb + (long)j * C2;

            f32x4 acc0 = {0.f,0.f,0.f,0.f}, acc1 = {0.f,0.f,0.f,0.f};
            f32x4 acc2 = {0.f,0.f,0.f,0.f}, acc3 = {0.f,0.f,0.f,0.f};

            #pragma unroll
            for (int kt = 0; kt < 2; ++kt) {
                const float4 y0 = *(const float4*)(pjE + kt * 32 + g * 8);
                const float4 y1 = *(const float4*)(pjE + kt * 32 + g * 8 + 4);
                float s0 = pmEf[kt][0] * fast_rcp(pmEf[kt][0] + y0.x);
                float s1 = pmEf[kt][1] * fast_rcp(pmEf[kt][1] + y0.y);
                float s2 = pmEf[kt][2] * fast_rcp(pmEf[kt][2] + y0.z);
                float s3 = pmEf[kt][3] * fast_rcp(pmEf[kt][3] + y0.w);
                float s4 = pmEf[kt][4] * fast_rcp(pmEf[kt][4] + y1.x);
                float s5 = pmEf[kt][5] * fast_rcp(pmEf[kt][5] + y1.y);
                float s6 = pmEf[kt][6] * fast_rcp(pmEf[kt][6] + y1.z);
                float s7 = pmEf[kt][7] * fast_rcp(pmEf[kt][7] + y1.w);
                uint u0 = __float_as_uint(s0), u1 = __float_as_uint(s1);
                uint u2 = __float_as_uint(s2), u3 = __float_as_uint(s3);
                uint u4 = __float_as_uint(s4), u5 = __float_as_uint(s5);
                uint u6 = __float_as_uint(s6), u7 = __float_as_uint(s7);
                uint l0 = __float_as_uint(s0 - __uint_as_float(u0 & 0xFFFF0000u));
                uint l1 = __float_as_uint(s1 - __uint_as_float(u1 & 0xFFFF0000u));
                uint l2 = __float_as_uint(s2 - __uint_as_float(u2 & 0xFFFF0000u));
                uint l3 = __float_as_uint(s3 - __uint_as_float(u3 & 0xFFFF0000u));
                uint l4 = __float_as_uint(s4 - __uint_as_float(u4 & 0xFFFF0000u));
                uint l5 = __float_as_uint(s5 - __uint_as_float(u5 & 0xFFFF0000u));
                uint l6 = __float_as_uint(s6 - __uint_as_float(u6 & 0xFFFF0000u));
                uint l7 = __float_as_uint(s7 - __uint_as_float(u7 & 0xFFFF0000u));
                int4v hiv = { (int)__builtin_amdgcn_perm(u1, u0, 0x07060302u),
                              (int)__builtin_amdgcn_perm(u3, u2, 0x07060302u),
                              (int)__builtin_amdgcn_perm(u5, u4, 0x07060302u),
                              (int)__builtin_amdgcn_perm(u7, u6, 0x07060302u) };
                int4v lov = { (int)__builtin_amdgcn_perm(l1, l0, 0x07060302u),
                              (int)__builtin_amdgcn_perm(l3, l2, 0x07060302u),
                              (int)__builtin_amdgcn_perm(l5, l4, 0x07060302u),
                              (int)__builtin_amdgcn_perm(l7, l6, 0x07060302u) };
                short8 bhi = __builtin_bit_cast(short8, hiv);
                short8 blo = __builtin_bit_cast(short8, lov);

                acc0 = __builtin_amdgcn_mfma_f32_16x16x32_bf16(ahi[0][kt], bhi, acc0, 0, 0, 0);
                acc0 = __builtin_amdgcn_mfma_f32_16x16x32_bf16(ahi[0][kt], blo, acc0, 0, 0, 0);
                acc0 = __builtin_amdgcn_mfma_f32_16x16x32_bf16(alo[0][kt], bhi, acc0, 0, 0, 0);
                acc1 = __builtin_amdgcn_mfma_f32_16x16x32_bf16(ahi[1][kt], bhi, acc1, 0, 0, 0);
                acc1 = __builtin_amdgcn_mfma_f32_16x16x32_bf16(ahi[1][kt], blo, acc1, 0, 0, 0);
                acc1 = __builtin_amdgcn_mfma_f32_16x16x32_bf16(alo[1][kt], bhi, acc1, 0, 0, 0);
                acc2 = __builtin_amdgcn_mfma_f32_16x16x32_bf16(ahi[2][kt], bhi, acc2, 0, 0, 0);
                acc2 = __builtin_amdgcn_mfma_f32_16x16x32_bf16(ahi[2][kt], blo, acc2, 0, 0, 0);
                acc2 = __builtin_amdgcn_mfma_f32_16x16x32_bf16(alo[2][kt], bhi, acc2, 0, 0, 0);
                acc3 = __builtin_amdgcn_mfma_f32_16x16x32_bf16(ahi[3][kt], bhi, acc3, 0, 0, 0);
                acc3 = __builtin_amdgcn_mfma_f32_16x16x32_bf16(ahi[3][kt], blo, acc3, 0, 0, 0);
                acc3 = __builtin_amdgcn_mfma_f32_16x16x32_bf16(alo[3][kt], bhi, acc3, 0, 0, 0);
            }

            float sq = 0.f;
            #pragma unroll
            for (int e = 0; e < 4; ++e) {
                sq = fmaf(acc0[e], acc0[e], sq);
                sq = fmaf(acc1[e], acc1[e], sq);
                sq = fmaf(acc2[e], acc2[e], sq);
                sq = fmaf(acc3[e], acc3[e], sq);
            }
            sq += __shfl_xor(sq, 16, 64);
            sq += __shfl_xor(sq, 32, 64);
            // pack: d2 (positive f32, uint-monotone) with index in low 10 bits
            if (lane < 16) {
                const int jj = jt * 16 + lane;
                d2u[jj] = (__float_as_uint(sq) & 0xFFFFFC00u) | (uint)jj;
            }
        }
    }
    __syncthreads();

    // ---- Phase B: top-24 candidates via packed min passes (both waves) ----
    uint v[16];
    #pragma unroll
    for (int q = 0; q < 16; ++q) v[q] = d2u[q * 64 + lane];

    int myCand = 0;
    #pragma unroll 1
    for (int k = 0; k < NCAND; ++k) {
        uint bv = v[0];
        #pragma unroll
        for (int q = 1; q < 16; ++q) bv = min(bv, v[q]);
        #pragma unroll
        for (int st = 0; st < 6; ++st)
            bv = min(bv, (uint)__shfl_xor((int)bv, 1 << st, 64));
        // winner uniform; remove from the slot that held it
        #pragma unroll
        for (int q = 0; q < 16; ++q)
            if (v[q] == bv) v[q] = 0xFFFFFFFFu;
        if (lane == k) myCand = (int)(bv & 0x3FFu);
    }

    // ---- Phase C: np-exact rescore (R6 bit-exact); wave wv: 12 candidates --
    float Acol[C2];
    #pragma unroll
    for (int c = 0; c < C2; ++c) Acol[c] = A[c * C2 + lane];

    #pragma unroll 1
    for (int t = wv * 12; t < wv * 12 + 12; ++t) {
        const int j = __shfl(myCand, t, 64);
        float psc = psb[(long)j * C2 + lane];
        float e = expf(psc - pm_own);
        float s_own = 1.0f / __fadd_rn(1.0f, e);     // sigmoid(pm-ps), lane=c
        sC[wv][lane] = s_own;
        LDS_FENCE();
        float wd = 0.f;
        #pragma unroll
        for (int c = 0; c < C2; ++c)                 // ascending c, single acc
            wd = fmaf(sC[wv][c], Acol[c], wd);
        const float t_own = __fmul_rn(wd, s_own);    // t_d = w_d * s_d, lane=d
        // numpy pairwise-8: r8[q] = ((t[q]+t[q+8])+t[q+16])+... (lanes 0..7)
        float r8 = t_own;
        #pragma unroll
        for (int blk = 1; blk < 8; ++blk)
            r8 = __fadd_rn(r8, __shfl(t_own, (lane & 7) + 8 * blk, 64));
        const float rr0 = __shfl(r8, 0, 64), rr1 = __shfl(r8, 1, 64);
        const float rr2 = __shfl(r8, 2, 64), rr3 = __shfl(r8, 3, 64);
        const float rr4 = __shfl(r8, 4, 64), rr5 = __shfl(r8, 5, 64);
        const float rr6 = __shfl(r8, 6, 64), rr7 = __shfl(r8, 7, 64);
        float dis2 = __fadd_rn(
            __fadd_rn(__fadd_rn(rr0, rr1), __fadd_rn(rr2, rr3)),
            __fadd_rn(__fadd_rn(rr4, rr5), __fadd_rn(rr6, rr7)));
        float disf = sqrtf(dis2);
        float ee = expf(disf);
        float cd = 1.0f / __fadd_rn(1.0f, ee);       // sigmoid(-dis)
        if (lane == 0) cdiffL[t] = cd;
    }
    __syncthreads();

    // ---- Final: wave 0 top-16 over 24 exact diffs (desc, index asc) ----
    if (wv == 0) {
        float myd = (lane < NCAND) ? cdiffL[lane] : -2.0f;
        int myj = (lane < NCAND) ? myCand : (1 << 20);

        const int obase = b * (NN * KK) + i * KK;    // index chunk (f32)
        const int vbase = 2 * NN * KK + obase;       // value chunk (f32)

        #pragma unroll 1
        for (int k = 0; k < KK; ++k) {
            float bd = myd;
            int bj = myj;
            #pragma unroll
            for (int st = 0; st < 6; ++st) {
                int msk = 1 << st;
                float od = __shfl_xor(bd, msk, 64);
                int oj = __shfl_xor(bj, msk, 64);
                bool better = (od > bd) || (od == bd && oj < bj);
                bd = better ? od : bd;
                bj = better ? oj : bj;
            }
            if (myj == bj) myd = -2.0f;              // candidate j's unique
            if (lane == 0) {
                out[obase + k] = (float)bj;
                out[vbase + k] = -bd;                // value = -topk(diff)
            }
        }
    }
}

extern "C" void kernel_launch(void* const* d_in, const int* in_sizes, int n_in,
                              void* d_out, int out_size, void* d_ws, size_t ws_size,
                              hipStream_t stream) {
    const float* X  = (const float*)d_in[0];
    const float* Wm = (const float*)d_in[1];
    const float* Ws = (const float*)d_in[2];
    const float* M  = (const float*)d_in[3];

    float* A   = (float*)d_ws;           // 4096 f   (16 KB)
    float* pm  = A + C2 * C2;            // 131072 f (512 KB)
    float* ps  = pm + 2 * NN * C2;       // 131072 f (512 KB)
    float* psE = ps + 2 * NN * C2;       // 131072 f (512 KB)  total ~1.52 MB
    float* out = (float*)d_out;          // f32: [idx 32768][val 32768]

    hipLaunchKernelGGL(buildA, dim3(16), dim3(256), 0, stream, M, A);
    hipLaunchKernelGGL(proj, dim3(2 * NN), dim3(128), 0, stream,
                       X, Wm, Ws, pm, ps, psE);
    hipLaunchKernelGGL(pair_topk, dim3(2 * NN), dim3(128), 0, stream,
                       pm, ps, psE, M, A, out);
}

// Round 13
// 127.410 us; speedup vs baseline: 1.1389x; 1.1389x over previous
//
#include <hip/hip_runtime.h>
#include <hip/hip_bf16.h>
#include <math.h>

#define NN 1024
#define CC 128
#define C2 64
#define KK 16
#define NCAND 24

#if __has_builtin(__builtin_amdgcn_exp2f)
#define EXP2F(x) __builtin_amdgcn_exp2f(x)
#else
#define EXP2F(x) exp2f(x)
#endif
#define LOG2E 1.4426950408889634f

typedef short short8 __attribute__((ext_vector_type(8)));
typedef float f32x4  __attribute__((ext_vector_type(4)));
typedef int   int4v  __attribute__((ext_vector_type(4)));
typedef unsigned int uint;

__device__ __forceinline__ float fast_rcp(float x) {
    return __builtin_amdgcn_rcpf(x);
}
__device__ __forceinline__ unsigned short f2bf(float x) {   // RNE f32->bf16
    unsigned int u = __float_as_uint(x);
    unsigned int r = (u + 0x7FFFu + ((u >> 16) & 1u)) >> 16;
    return (unsigned short)r;
}
__device__ __forceinline__ float bf2f(unsigned short h) {
    return __uint_as_float(((unsigned int)h) << 16);
}

// In-wave LDS write->read visibility: wait LDS ops, pin compiler order.
#define LDS_FENCE() do { \
    asm volatile("s_waitcnt lgkmcnt(0)" ::: "memory"); \
    __builtin_amdgcn_sched_barrier(0); } while (0)

// ---------------- K0: A = M^T M, f32, ascending-r fmaf chain (np-exact) ----
__global__ __launch_bounds__(256) void buildA(const float* __restrict__ M,
                                              float* __restrict__ A) {
    const int e = blockIdx.x * 256 + threadIdx.x;    // 4096 entries
    const int c = e >> 6, d = e & 63;
    float acc = 0.f;
    #pragma unroll 8
    for (int r = 0; r < C2; ++r)
        acc = fmaf(M[r * C2 + c], M[r * C2 + d], acc);
    A[e] = acc;                                      // A[c][d] row-major
}

// ---------------- K1: projections + logmap, f32 (np-exact) + psE -----------
__global__ __launch_bounds__(128) void proj(
        const float* __restrict__ X,
        const float* __restrict__ Wm,
        const float* __restrict__ Ws,
        float* __restrict__ pm,
        float* __restrict__ ps,
        float* __restrict__ psE) {
    const int bn = blockIdx.x;           // b*1024 + n
    const int b  = bn >> 10;
    const int n  = bn & (NN - 1);
    const int t  = threadIdx.x;          // 0..127

    __shared__ float xv[CC];
    xv[t] = X[b * CC * NN + t * NN + n];
    __syncthreads();

    const int d = t & (C2 - 1);
    const float* wr = ((t < C2) ? Wm : Ws) + d * CC;
    float acc = 0.f;
    #pragma unroll
    for (int c = 0; c < CC; ++c)
        acc = fmaf(wr[c], xv[c], acc);   // sequential k-order, single acc

    float a = __fadd_rn(fabsf(acc), 1e-10f);
    float l = logf(a);
    float r = (acc > 0.f) ? l : ((acc < 0.f) ? -l : 0.f);
    if (t < C2) {
        pm[bn * C2 + d] = r;
    } else {
        ps[bn * C2 + d] = r;
        psE[bn * C2 + d] = EXP2F(r * LOG2E);   // e^ps (proxy pass only)
    }
}

// Build bhi/blo bf16 fragments from 8 sigmoids (truncation split; proxy only)
#define SIG_PACK(Y0, Y1, KT, BHI, BLO) do {                                   \
    float s0 = pmEf[KT][0] * fast_rcp(pmEf[KT][0] + (Y0).x);                  \
    float s1 = pmEf[KT][1] * fast_rcp(pmEf[KT][1] + (Y0).y);                  \
    float s2 = pmEf[KT][2] * fast_rcp(pmEf[KT][2] + (Y0).z);                  \
    float s3 = pmEf[KT][3] * fast_rcp(pmEf[KT][3] + (Y0).w);                  \
    float s4 = pmEf[KT][4] * fast_rcp(pmEf[KT][4] + (Y1).x);                  \
    float s5 = pmEf[KT][5] * fast_rcp(pmEf[KT][5] + (Y1).y);                  \
    float s6 = pmEf[KT][6] * fast_rcp(pmEf[KT][6] + (Y1).z);                  \
    float s7 = pmEf[KT][7] * fast_rcp(pmEf[KT][7] + (Y1).w);                  \
    uint u0 = __float_as_uint(s0), u1 = __float_as_uint(s1);                  \
    uint u2 = __float_as_uint(s2), u3 = __float_as_uint(s3);                  \
    uint u4 = __float_as_uint(s4), u5 = __float_as_uint(s5);                  \
    uint u6 = __float_as_uint(s6), u7 = __float_as_uint(s7);                  \
    uint l0 = __float_as_uint(s0 - __uint_as_float(u0 & 0xFFFF0000u));        \
    uint l1 = __float_as_uint(s1 - __uint_as_float(u1 & 0xFFFF0000u));        \
    uint l2 = __float_as_uint(s2 - __uint_as_float(u2 & 0xFFFF0000u));        \
    uint l3 = __float_as_uint(s3 - __uint_as_float(u3 & 0xFFFF0000u));        \
    uint l4 = __float_as_uint(s4 - __uint_as_float(u4 & 0xFFFF0000u));        \
    uint l5 = __float_as_uint(s5 - __uint_as_float(u5 & 0xFFFF0000u));        \
    uint l6 = __float_as_uint(s6 - __uint_as_float(u6 & 0xFFFF0000u));        \
    uint l7 = __float_as_uint(s7 - __uint_as_float(u7 & 0xFFFF0000u));        \
    int4v hiv = { (int)__builtin_amdgcn_perm(u1, u0, 0x07060302u),            \
                  (int)__builtin_amdgcn_perm(u3, u2, 0x07060302u),            \
                  (int)__builtin_amdgcn_perm(u5, u4, 0x07060302u),            \
                  (int)__builtin_amdgcn_perm(u7, u6, 0x07060302u) };          \
    int4v lov = { (int)__builtin_amdgcn_perm(l1, l0, 0x07060302u),            \
                  (int)__builtin_amdgcn_perm(l3, l2, 0x07060302u),            \
                  (int)__builtin_amdgcn_perm(l5, l4, 0x07060302u),            \
                  (int)__builtin_amdgcn_perm(l7, l6, 0x07060302u) };          \
    BHI = __builtin_bit_cast(short8, hiv);                                    \
    BLO = __builtin_bit_cast(short8, lov);                                    \
} while (0)

#define MFMA12(AC, KT, BHI, BLO)                                                        \
    AC[0] = __builtin_amdgcn_mfma_f32_16x16x32_bf16(ahi[0][KT], BHI, AC[0], 0, 0, 0);   \
    AC[0] = __builtin_amdgcn_mfma_f32_16x16x32_bf16(ahi[0][KT], BLO, AC[0], 0, 0, 0);   \
    AC[0] = __builtin_amdgcn_mfma_f32_16x16x32_bf16(alo[0][KT], BHI, AC[0], 0, 0, 0);   \
    AC[1] = __builtin_amdgcn_mfma_f32_16x16x32_bf16(ahi[1][KT], BHI, AC[1], 0, 0, 0);   \
    AC[1] = __builtin_amdgcn_mfma_f32_16x16x32_bf16(ahi[1][KT], BLO, AC[1], 0, 0, 0);   \
    AC[1] = __builtin_amdgcn_mfma_f32_16x16x32_bf16(alo[1][KT], BHI, AC[1], 0, 0, 0);   \
    AC[2] = __builtin_amdgcn_mfma_f32_16x16x32_bf16(ahi[2][KT], BHI, AC[2], 0, 0, 0);   \
    AC[2] = __builtin_amdgcn_mfma_f32_16x16x32_bf16(ahi[2][KT], BLO, AC[2], 0, 0, 0);   \
    AC[2] = __builtin_amdgcn_mfma_f32_16x16x32_bf16(alo[2][KT], BHI, AC[2], 0, 0, 0);   \
    AC[3] = __builtin_amdgcn_mfma_f32_16x16x32_bf16(ahi[3][KT], BHI, AC[3], 0, 0, 0);   \
    AC[3] = __builtin_amdgcn_mfma_f32_16x16x32_bf16(ahi[3][KT], BLO, AC[3], 0, 0, 0);   \
    AC[3] = __builtin_amdgcn_mfma_f32_16x16x32_bf16(alo[3][KT], BHI, AC[3], 0, 0, 0);

// ---------------- K2: 1 row/wave, 4 waves/block, 512 blocks ----------------
//  A: proxy dis2 via bf16 3-term-split MFMA; 2 j-tiles/iter (8 indep chains),
//     explicit next-iter prefetch, per-lane partials to LDS (no per-tile shfl)
//  B: per-wave top-24 candidates: sum 4 partials + packed-uint min passes
//  C: per-wave np-exact rescore (R6 bit-exact op order), 24 candidates
//  F: per-wave top-16 on exact diff (desc, index asc) -> out
__global__ __launch_bounds__(256, 2) void pair_topk(
        const float* __restrict__ pm,
        const float* __restrict__ ps,
        const float* __restrict__ psE,
        const float* __restrict__ Mf,
        const float* __restrict__ A,
        float* __restrict__ out) {
    const int tid  = threadIdx.x;
    const int wv   = tid >> 6;           // 0..3
    const int lane = tid & 63;
    const int g    = lane >> 4;          // k-group 0..3
    const int lj   = lane & 15;          // col (B) / row (A) within tile

    const int bi = blockIdx.x * 4 + wv;  // row 0..2047
    const int b  = bi >> 10;
    const int i  = bi & (NN - 1);

    __shared__ float d2p[4][4][NN + 8];  // per-wave per-group partials (~66 KB)
    __shared__ float sC[4][C2];
    __shared__ float cdiffL[4][NCAND];

    const float* psb  = ps  + b * NN * C2;
    const float* psEb = psE + b * NN * C2;

    const float pm_own = pm[bi * C2 + lane];         // exact (phase C)

    float pmEf[2][8];
    #pragma unroll
    for (int kt = 0; kt < 2; ++kt) {
        const float4 a0 = *(const float4*)(pm + bi * C2 + kt * 32 + g * 8);
        const float4 a1 = *(const float4*)(pm + bi * C2 + kt * 32 + g * 8 + 4);
        pmEf[kt][0] = EXP2F(a0.x * LOG2E); pmEf[kt][1] = EXP2F(a0.y * LOG2E);
        pmEf[kt][2] = EXP2F(a0.z * LOG2E); pmEf[kt][3] = EXP2F(a0.w * LOG2E);
        pmEf[kt][4] = EXP2F(a1.x * LOG2E); pmEf[kt][5] = EXP2F(a1.y * LOG2E);
        pmEf[kt][6] = EXP2F(a1.z * LOG2E); pmEf[kt][7] = EXP2F(a1.w * LOG2E);
    }

    // ---- Phase A (scoped so M fragments die before phase C) ----
    {
        short8 ahi[4][2], alo[4][2];     // M rows hi/lo bf16 (RNE, once)
        #pragma unroll
        for (int rt = 0; rt < 4; ++rt) {
            #pragma unroll
            for (int kt = 0; kt < 2; ++kt) {
                const float* mrow = Mf + (rt * 16 + lj) * C2 + kt * 32 + g * 8;
                const float4 m0 = *(const float4*)mrow;
                const float4 m1 = *(const float4*)(mrow + 4);
                float mv[8] = {m0.x, m0.y, m0.z, m0.w, m1.x, m1.y, m1.z, m1.w};
                #pragma unroll
                for (int e = 0; e < 8; ++e) {
                    unsigned short h = f2bf(mv[e]);
                    ahi[rt][kt][e] = (short)h;
                    alo[rt][kt][e] = (short)f2bf(mv[e] - bf2f(h));
                }
            }
        }

        // prefetch regs for 2 tiles: [tile][kt][vec]
        const float* p0 = psEb + (long)(0 * 16 + lj) * C2 + g * 8;
        const float* p1 = psEb + (long)(1 * 16 + lj) * C2 + g * 8;
        float4 cA0 = *(const float4*)(p0);      float4 cA1 = *(const float4*)(p0 + 4);
        float4 cA2 = *(const float4*)(p0 + 32); float4 cA3 = *(const float4*)(p0 + 36);
        float4 cB0 = *(const float4*)(p1);      float4 cB1 = *(const float4*)(p1 + 4);
        float4 cB2 = *(const float4*)(p1 + 32); float4 cB3 = *(const float4*)(p1 + 36);

        #pragma unroll 1
        for (int it = 0; it < 32; ++it) {
            float4 nA0, nA1, nA2, nA3, nB0, nB1, nB2, nB3;
            if (it < 31) {                       // issue next-iter loads EARLY
                const float* q0 = psEb + (long)((it * 2 + 2) * 16 + lj) * C2 + g * 8;
                const float* q1 = psEb + (long)((it * 2 + 3) * 16 + lj) * C2 + g * 8;
                nA0 = *(const float4*)(q0);      nA1 = *(const float4*)(q0 + 4);
                nA2 = *(const float4*)(q0 + 32); nA3 = *(const float4*)(q0 + 36);
                nB0 = *(const float4*)(q1);      nB1 = *(const float4*)(q1 + 4);
                nB2 = *(const float4*)(q1 + 32); nB3 = *(const float4*)(q1 + 36);
            }

            // build B-fragments for both tiles (independent)
            short8 hA0, lA0, hA1, lA1, hB0, lB0, hB1, lB1;
            SIG_PACK(cA0, cA1, 0, hA0, lA0);
            SIG_PACK(cA2, cA3, 1, hA1, lA1);
            SIG_PACK(cB0, cB1, 0, hB0, lB0);
            SIG_PACK(cB2, cB3, 1, hB1, lB1);

            f32x4 accA[4] = {{0,0,0,0},{0,0,0,0},{0,0,0,0},{0,0,0,0}};
            f32x4 accB[4] = {{0,0,0,0},{0,0,0,0},{0,0,0,0},{0,0,0,0}};

            __builtin_amdgcn_s_setprio(1);
            MFMA12(accA, 0, hA0, lA0)
            MFMA12(accB, 0, hB0, lB0)
            MFMA12(accA, 1, hA1, lA1)
            MFMA12(accB, 1, hB1, lB1)
            __builtin_amdgcn_s_setprio(0);

            float sqA = 0.f, sqB = 0.f;
            #pragma unroll
            for (int e = 0; e < 4; ++e) {
                sqA = fmaf(accA[0][e], accA[0][e], sqA);
                sqA = fmaf(accA[1][e], accA[1][e], sqA);
                sqA = fmaf(accA[2][e], accA[2][e], sqA);
                sqA = fmaf(accA[3][e], accA[3][e], sqA);
                sqB = fmaf(accB[0][e], accB[0][e], sqB);
                sqB = fmaf(accB[1][e], accB[1][e], sqB);
                sqB = fmaf(accB[2][e], accB[2][e], sqB);
                sqB = fmaf(accB[3][e], accB[3][e], sqB);
            }
            // per-lane partial (16 of 64 rows) -> LDS; reduce deferred to B
            d2p[wv][g][(it * 2 + 0) * 16 + lj] = sqA;
            d2p[wv][g][(it * 2 + 1) * 16 + lj] = sqB;

            cA0 = nA0; cA1 = nA1; cA2 = nA2; cA3 = nA3;
            cB0 = nB0; cB1 = nB1; cB2 = nB2; cB3 = nB3;
        }
    }
    LDS_FENCE();

    // ---- Phase B: sum partials, pack, top-24 via packed-uint min passes ----
    uint v[16];
    #pragma unroll
    for (int q = 0; q < 16; ++q) {
        const int j = q * 64 + lane;
        float s = __fadd_rn(__fadd_rn(d2p[wv][0][j], d2p[wv][1][j]),
                            __fadd_rn(d2p[wv][2][j], d2p[wv][3][j]));
        v[q] = (__float_as_uint(s) & 0xFFFFFC00u) | (uint)j;
    }

    int myCand = 0;
    #pragma unroll 1
    for (int k = 0; k < NCAND; ++k) {
        uint bv = v[0];
        #pragma unroll
        for (int q = 1; q < 16; ++q) bv = min(bv, v[q]);
        #pragma unroll
        for (int st = 0; st < 6; ++st)
            bv = min(bv, (uint)__shfl_xor((int)bv, 1 << st, 64));
        #pragma unroll
        for (int q = 0; q < 16; ++q)
            if (v[q] == bv) v[q] = 0xFFFFFFFFu;
        if (lane == k) myCand = (int)(bv & 0x3FFu);
    }

    // ---- Phase C: np-exact rescore (R6 bit-exact), 24 candidates/wave ----
    float Acol[C2];
    #pragma unroll
    for (int c = 0; c < C2; ++c) Acol[c] = A[c * C2 + lane];

    #pragma unroll 1
    for (int t = 0; t < NCAND; ++t) {
        const int j = __shfl(myCand, t, 64);
        float psc = psb[(long)j * C2 + lane];
        float e = expf(psc - pm_own);
        float s_own = 1.0f / __fadd_rn(1.0f, e);     // sigmoid(pm-ps), lane=c
        sC[wv][lane] = s_own;
        LDS_FENCE();
        float wd = 0.f;
        #pragma unroll
        for (int c = 0; c < C2; ++c)                 // ascending c, single acc
            wd = fmaf(sC[wv][c], Acol[c], wd);
        const float t_own = __fmul_rn(wd, s_own);    // t_d = w_d * s_d, lane=d
        // numpy pairwise-8 via shfl (same op order as np)
        float r8 = t_own;
        #pragma unroll
        for (int blk = 1; blk < 8; ++blk)
            r8 = __fadd_rn(r8, __shfl(t_own, (lane & 7) + 8 * blk, 64));
        const float rr0 = __shfl(r8, 0, 64), rr1 = __shfl(r8, 1, 64);
        const float rr2 = __shfl(r8, 2, 64), rr3 = __shfl(r8, 3, 64);
        const float rr4 = __shfl(r8, 4, 64), rr5 = __shfl(r8, 5, 64);
        const float rr6 = __shfl(r8, 6, 64), rr7 = __shfl(r8, 7, 64);
        float dis2 = __fadd_rn(
            __fadd_rn(__fadd_rn(rr0, rr1), __fadd_rn(rr2, rr3)),
            __fadd_rn(__fadd_rn(rr4, rr5), __fadd_rn(rr6, rr7)));
        float disf = sqrtf(dis2);
        float ee = expf(disf);
        float cd = 1.0f / __fadd_rn(1.0f, ee);       // sigmoid(-dis)
        if (lane == 0) cdiffL[wv][t] = cd;
    }
    LDS_FENCE();

    // ---- Final: per-wave top-16 over 24 exact diffs (desc, index asc) ----
    float myd = (lane < NCAND) ? cdiffL[wv][lane] : -2.0f;
    int myj = (lane < NCAND) ? myCand : (1 << 20);

    const int obase = b * (NN * KK) + i * KK;        // index chunk (f32)
    const int vbase = 2 * NN * KK + obase;           // value chunk (f32)

    #pragma unroll 1
    for (int k = 0; k < KK; ++k) {
        float bd = myd;
        int bj = myj;
        #pragma unroll
        for (int st = 0; st < 6; ++st) {
            int msk = 1 << st;
            float od = __shfl_xor(bd, msk, 64);
            int oj = __shfl_xor(bj, msk, 64);
            bool better = (od > bd) || (od == bd && oj < bj);
            bd = better ? od : bd;
            bj = better ? oj : bj;
        }
        if (myj == bj) myd = -2.0f;                  // candidate j's unique
        if (lane == 0) {
            out[obase + k] = (float)bj;
            out[vbase + k] = -bd;                    // value = -topk(diff)
        }
    }
}

extern "C" void kernel_launch(void* const* d_in, const int* in_sizes, int n_in,
                              void* d_out, int out_size, void* d_ws, size_t ws_size,
                              hipStream_t stream) {
    const float* X  = (const float*)d_in[0];
    const float* Wm = (const float*)d_in[1];
    const float* Ws = (const float*)d_in[2];
    const float* M  = (const float*)d_in[3];

    float* A   = (float*)d_ws;           // 4096 f   (16 KB)
    float* pm  = A + C2 * C2;            // 131072 f (512 KB)
    float* ps  = pm + 2 * NN * C2;       // 131072 f (512 KB)
    float* psE = ps + 2 * NN * C2;       // 131072 f (512 KB)  total ~1.52 MB
    float* out = (float*)d_out;          // f32: [idx 32768][val 32768]

    hipLaunchKernelGGL(buildA, dim3(16), dim3(256), 0, stream, M, A);
    hipLaunchKernelGGL(proj, dim3(2 * NN), dim3(128), 0, stream,
                       X, Wm, Ws, pm, ps, psE);
    hipLaunchKernelGGL(pair_topk, dim3(512), dim3(256), 0, stream,
                       pm, ps, psE, M, A, out);
}